// Round 6
// baseline (304.570 us; speedup 1.0000x reference)
//
#include <hip/hip_runtime.h>
#include <hip/hip_bf16.h>
#include <math.h>

#define D_MODEL 1024
#define HS 2048
#define HE 1024
#define NEXP 8
#define NTOK 4096
#define NSLOT 8192

typedef __attribute__((ext_vector_type(4))) float f32x4;
typedef __attribute__((ext_vector_type(8))) short bf16x8;

__device__ __forceinline__ short f2b(float f) {
  __hip_bfloat16 h = __float2bfloat16(f);
  return *reinterpret_cast<short*>(&h);
}
__device__ __forceinline__ float b2f(short s) {
  return __bfloat162float(*reinterpret_cast<__hip_bfloat16*>(&s));
}

__device__ __forceinline__ void gl_lds16(const short* g, short* l) {
  __builtin_amdgcn_global_load_lds(
      (const __attribute__((address_space(1))) void*)g,
      (__attribute__((address_space(3))) void*)l, 16, 0, 0);
}

// ================= PREP: one launch does cvt_x + 5 transposes + router ======
// Block roles by blockIdx.x:
//  [0,2048)      cvt_x (8 f32 -> bf16 per thread)
//  [2048,2560)   w1 -> w13I (RMAP 1)
//  [2560,3072)   w3 -> w13I (RMAP 2)
//  [3072,3584)   w2 -> w2T  (RMAP 0)
//  [3584,5632)   W1e -> W1eT (z = expert)
//  [5632,7680)   W2e -> W2eT
//  [7680,8704)   router (4 tokens/block, wave per token)

__device__ void transpose_tile(const float* __restrict__ in, short* __restrict__ out,
                               int R, int C, int bx, int by, int bz, int rmap,
                               float (*tile)[69], int t) {
  const int c0 = bx * 64;
  const int r0 = by * 64;
  const size_t bo = (size_t)bz * R * C;
  const int lr = t >> 4;
  const int lc4 = (t & 15) * 4;
#pragma unroll
  for (int i = 0; i < 4; i++) {
    const float4 v = *(const float4*)&in[bo + (size_t)(r0 + lr + i * 16) * C + c0 + lc4];
    tile[lc4 + 0][lr + i * 16] = v.x;
    tile[lc4 + 1][lr + i * 16] = v.y;
    tile[lc4 + 2][lr + i * 16] = v.z;
    tile[lc4 + 3][lr + i * 16] = v.w;
  }
  __syncthreads();
#pragma unroll
  for (int i = 0; i < 4; i++) {
    const int oc = (t >> 4) + i * 16;
    const int or4 = (t & 15) * 4;
    short4 o;
    o.x = f2b(tile[oc][or4 + 0]);
    o.y = f2b(tile[oc][or4 + 1]);
    o.z = f2b(tile[oc][or4 + 2]);
    o.w = f2b(tile[oc][or4 + 3]);
    const int c = c0 + oc;
    size_t orow;
    if (rmap == 0) orow = bo + (size_t)c * R;
    else orow = (size_t)((c >> 5) * 64 + (rmap == 2 ? 32 : 0) + (c & 31)) * R;
    *(short4*)&out[orow + r0 + or4] = o;
  }
}

__device__ void router_block(const float* __restrict__ x, const float* __restrict__ temb,
                             const float* __restrict__ rw, const float* __restrict__ rbias,
                             int* __restrict__ topk, float* __restrict__ gates,
                             int bb, int tid) {
  const int t = (bb * 256 + tid) >> 6;
  const int lane = tid & 63;
  const float* xr = x + (size_t)t * D_MODEL;
  const float* tr = temb + (size_t)(t >> 10) * D_MODEL;  // T=1024
  float acc[NEXP] = {};
#pragma unroll
  for (int i = 0; i < 4; i++) {
    const int j = i * 256 + lane * 4;
    const float4 xv = *(const float4*)&xr[j];
    const float4 tv = *(const float4*)&tr[j];
    const float* wx = rw + (size_t)j * NEXP;
    const float* wt = rw + (size_t)(D_MODEL + j) * NEXP;
    const float xa[4] = {xv.x, xv.y, xv.z, xv.w};
    const float ta[4] = {tv.x, tv.y, tv.z, tv.w};
#pragma unroll
    for (int u = 0; u < 4; u++)
#pragma unroll
      for (int e = 0; e < NEXP; e++)
        acc[e] += xa[u] * wx[u * NEXP + e] + ta[u] * wt[u * NEXP + e];
  }
#pragma unroll
  for (int off = 32; off; off >>= 1)
#pragma unroll
    for (int e = 0; e < NEXP; e++) acc[e] += __shfl_xor(acc[e], off);
  if (lane == 0) {
    float s[NEXP], sel[NEXP];
#pragma unroll
    for (int e = 0; e < NEXP; e++) {
      s[e] = 1.f / (1.f + expf(-acc[e]));
      sel[e] = s[e] + rbias[e];
    }
    int i0 = 0;
#pragma unroll
    for (int e = 1; e < NEXP; e++) if (sel[e] > sel[i0]) i0 = e;
    int i1 = (i0 == 0) ? 1 : 0;
#pragma unroll
    for (int e = 0; e < NEXP; e++) if (e != i0 && sel[e] > sel[i1]) i1 = e;
    float s0 = s[i0], s1 = s[i1], den = s0 + s1;
    float g0, g1;
    if (den > 1e-9f) { g0 = s0 / (den + 1e-9f); g1 = s1 / (den + 1e-9f); }
    else { g0 = 0.5f; g1 = 0.5f; }
    topk[t * 2] = i0; topk[t * 2 + 1] = i1;
    gates[t * 2] = g0; gates[t * 2 + 1] = g1;
  }
}

__global__ __launch_bounds__(256) void prep_kernel(
    const float* __restrict__ x, const float* __restrict__ temb,
    const float* __restrict__ rw, const float* __restrict__ rbias,
    const float* __restrict__ w1, const float* __restrict__ w3,
    const float* __restrict__ w2, const float* __restrict__ W1e,
    const float* __restrict__ W2e,
    short* __restrict__ xb, short* __restrict__ w13I, short* __restrict__ w2T,
    short* __restrict__ W1eT, short* __restrict__ W2eT,
    int* __restrict__ topk, float* __restrict__ gates) {
  __shared__ float tile[64][69];
  const int b = blockIdx.x;
  const int t = threadIdx.x;
  if (b < 2048) {
    const size_t base = ((size_t)b * 256 + t) * 8;
    const float4 v0 = *(const float4*)&x[base];
    const float4 v1 = *(const float4*)&x[base + 4];
    short4 o0, o1;
    o0.x = f2b(v0.x); o0.y = f2b(v0.y); o0.z = f2b(v0.z); o0.w = f2b(v0.w);
    o1.x = f2b(v1.x); o1.y = f2b(v1.y); o1.z = f2b(v1.z); o1.w = f2b(v1.w);
    *(short4*)&xb[base] = o0;
    *(short4*)&xb[base + 4] = o1;
  } else if (b < 2560) {
    const int bb = b - 2048;
    transpose_tile(w1, w13I, D_MODEL, HS, bb & 31, bb >> 5, 0, 1, tile, t);
  } else if (b < 3072) {
    const int bb = b - 2560;
    transpose_tile(w3, w13I, D_MODEL, HS, bb & 31, bb >> 5, 0, 2, tile, t);
  } else if (b < 3584) {
    const int bb = b - 3072;
    transpose_tile(w2, w2T, HS, D_MODEL, bb & 15, bb >> 4, 0, 0, tile, t);
  } else if (b < 5632) {
    const int bb = b - 3584;
    transpose_tile(W1e, W1eT, D_MODEL, HE, bb & 15, (bb >> 4) & 15, bb >> 8, 0, tile, t);
  } else if (b < 7680) {
    const int bb = b - 5632;
    transpose_tile(W2e, W2eT, HE, D_MODEL, bb & 15, (bb >> 4) & 15, bb >> 8, 0, tile, t);
  } else {
    router_block(x, temb, rw, rbias, topk, gates, b - 7680, t);
  }
}

// ---------------- grouping: hist + scan + fill in one block ----------------
__global__ __launch_bounds__(1024) void group_kernel(const int* __restrict__ topk,
                                                     int* __restrict__ perm,
                                                     int* __restrict__ offs) {
  __shared__ int cnt[NEXP], cur[NEXP];
  const int t = threadIdx.x;
  if (t < NEXP) cnt[t] = 0;
  __syncthreads();
  int mye[8];
#pragma unroll
  for (int i = 0; i < 8; i++) {
    mye[i] = topk[i * 1024 + t];
    atomicAdd(&cnt[mye[i]], 1);
  }
  __syncthreads();
  if (t == 0) {
    int a = 0;
    for (int e = 0; e < NEXP; e++) { offs[e] = a; cur[e] = a; a += cnt[e]; }
    offs[NEXP] = a;
  }
  __syncthreads();
#pragma unroll
  for (int i = 0; i < 8; i++) {
    int pos = atomicAdd(&cur[mye[i]], 1);
    perm[pos] = i * 1024 + t;
  }
}

// ============ 256x256 BK=64 8-wave per-phase-barrier pipelined GEMM ==========
// MODE 0 (G1): A=xb dense [m0+trow], B=w13I, silu(a)*b -> ubuf. grid(16,16).
// MODE 1: A=xb gathered perm>>1, B=W1eT[e], GELU -> hexpb[gi]. grid(4,32,8).
// MODE 2: A=hexpb slot-order dense, B=W2eT[e], gate*scatter -> yb. grid(4,32,8).
// K=1024 (16 K-tiles) for all. Per K-tile 4 phases, each:
//   {ds_read frags; stage one 2-load unit; [vmcnt ph1/ph4]; barrier;
//    lgkmcnt(0); sched_barrier; setprio(1); 16 MFMA; setprio(0); barrier}.
// Stage units of tile t+1 in order {B0,B1,A.i0,A.i1}; counted vmcnt(2) never
// drains in-loop (T4). LDS 128 KiB, XOR-swizzled both sides (rule 21).
template <int MODE>
__global__ __launch_bounds__(512, 1) void moe_gemm_8ph(
    const short* __restrict__ A, const short* __restrict__ B, short* __restrict__ U,
    const int* __restrict__ perm, const int* __restrict__ offs,
    const float* __restrict__ gates) {
  extern __shared__ short lds[];
  const int td = threadIdx.x;
  const int bx = blockIdx.x;
  const int m0 = blockIdx.y * 256;
  int rbeg = 0, rend = 0;
  const short* Bbase;
  if (MODE == 0) {
    Bbase = B + (size_t)bx * 256 * 1024;
  } else {
    const int e = blockIdx.z;
    rbeg = offs[e]; rend = offs[e + 1];
    if (m0 >= rend - rbeg) return;
    Bbase = B + ((size_t)e * 1024 + bx * 256) * 1024;
  }

  // staging source pointers (global col pre-swizzled, rule 21)
  const int srow = td >> 3;
  const int colsw8 = ((td & 7) ^ (srow & 7)) * 8;
  const short* ap[2][2];
  const short* bp[2][2];
#pragma unroll
  for (int h = 0; h < 2; h++)
#pragma unroll
    for (int i = 0; i < 2; i++) {
      const int trow = h * 128 + i * 64 + srow;
      int grow;
      if (MODE == 0) grow = m0 + trow;
      else if (MODE == 1) grow = perm[min(rbeg + m0 + trow, rend - 1)] >> 1;
      else grow = min(rbeg + m0 + trow, rend - 1);
      ap[h][i] = A + (size_t)grow * 1024 + colsw8;
      bp[h][i] = Bbase + (size_t)trow * 1024 + colsw8;
    }

#define SB0(t_, b_)                                                        \
  do {                                                                     \
    gl_lds16(bp[0][0] + (t_) * 64, lds + (b_) * 32768 + 16384 + td * 8);   \
    gl_lds16(bp[0][1] + (t_) * 64, lds + (b_) * 32768 + 16384 + 4096 + td * 8); \
  } while (0)
#define SB1(t_, b_)                                                        \
  do {                                                                     \
    gl_lds16(bp[1][0] + (t_) * 64, lds + (b_) * 32768 + 16384 + 8192 + td * 8); \
    gl_lds16(bp[1][1] + (t_) * 64, lds + (b_) * 32768 + 16384 + 8192 + 4096 + td * 8); \
  } while (0)
#define SAI0(t_, b_)                                                       \
  do {                                                                     \
    gl_lds16(ap[0][0] + (t_) * 64, lds + (b_) * 32768 + td * 8);           \
    gl_lds16(ap[1][0] + (t_) * 64, lds + (b_) * 32768 + 8192 + td * 8);    \
  } while (0)
#define SAI1(t_, b_)                                                       \
  do {                                                                     \
    gl_lds16(ap[0][1] + (t_) * 64, lds + (b_) * 32768 + 4096 + td * 8);    \
    gl_lds16(ap[1][1] + (t_) * 64, lds + (b_) * 32768 + 8192 + 4096 + td * 8); \
  } while (0)

  const int l = td & 63;
  const int wid = td >> 6;
  const int mh = wid >> 2;
  const int wn4 = wid & 3;
  const int lr = l & 15;
  const int bhsel = wn4 >> 1;
  const int bnr = (wn4 & 1) * 64;
  const int swzk0 = ((0 + (l >> 4) * 16) ^ ((l & 7) << 4)) >> 1;
  const int swzk1 = ((64 + (l >> 4) * 16) ^ ((l & 7) << 4)) >> 1;

#define LDA(mf_, swz_) (*(const bf16x8*)&Ah[(unsigned)(((mf_)*16 + lr) * 64) + (swz_)])
#define LDB(nf_, swz_) (*(const bf16x8*)&Bh[(unsigned)((bnr + (nf_)*16 + lr) * 64) + (swz_)])
#define MMROW(mf_, a_)                                                                 \
  acc[mf_][0] = __builtin_amdgcn_mfma_f32_16x16x32_bf16(a_, b0, acc[mf_][0], 0, 0, 0); \
  acc[mf_][1] = __builtin_amdgcn_mfma_f32_16x16x32_bf16(a_, b1, acc[mf_][1], 0, 0, 0); \
  acc[mf_][2] = __builtin_amdgcn_mfma_f32_16x16x32_bf16(a_, b2, acc[mf_][2], 0, 0, 0); \
  acc[mf_][3] = __builtin_amdgcn_mfma_f32_16x16x32_bf16(a_, b3, acc[mf_][3], 0, 0, 0)

#define PH_TAIL                                   \
  __builtin_amdgcn_s_barrier();                   \
  asm volatile("s_waitcnt lgkmcnt(0)" ::: "memory"); \
  __builtin_amdgcn_sched_barrier(0);              \
  __builtin_amdgcn_s_setprio(1)
#define PH_END                                    \
  __builtin_amdgcn_s_setprio(0);                  \
  __builtin_amdgcn_s_barrier();                   \
  __builtin_amdgcn_sched_barrier(0)

  f32x4 acc[8][4] = {};

  SB0(0, 0); SB1(0, 0); SAI0(0, 0); SAI1(0, 0);
  asm volatile("s_waitcnt vmcnt(2)" ::: "memory");
  __builtin_amdgcn_s_barrier();

  for (int t = 0; t < 16; ++t) {
    const int p = t & 1, q = p ^ 1;
    const short* Ah = lds + p * 32768 + mh * 8192;
    const short* Bh = lds + p * 32768 + 16384 + bhsel * 8192;
    bf16x8 b0, b1, b2, b3, a0, a1, a2, a3;
    // ph1
    b0 = LDB(0, swzk0); b1 = LDB(1, swzk0); b2 = LDB(2, swzk0); b3 = LDB(3, swzk0);
    a0 = LDA(0, swzk0); a1 = LDA(1, swzk0); a2 = LDA(2, swzk0); a3 = LDA(3, swzk0);
    if (t < 15) {
      SB0(t + 1, q);
      asm volatile("s_waitcnt vmcnt(2)" ::: "memory");
    } else {
      asm volatile("s_waitcnt vmcnt(0)" ::: "memory");
    }
    PH_TAIL;
    MMROW(0, a0); MMROW(1, a1); MMROW(2, a2); MMROW(3, a3);
    PH_END;
    // ph2
    a0 = LDA(4, swzk0); a1 = LDA(5, swzk0); a2 = LDA(6, swzk0); a3 = LDA(7, swzk0);
    if (t < 15) SB1(t + 1, q);
    PH_TAIL;
    MMROW(4, a0); MMROW(5, a1); MMROW(6, a2); MMROW(7, a3);
    PH_END;
    // ph3
    b0 = LDB(0, swzk1); b1 = LDB(1, swzk1); b2 = LDB(2, swzk1); b3 = LDB(3, swzk1);
    a0 = LDA(0, swzk1); a1 = LDA(1, swzk1); a2 = LDA(2, swzk1); a3 = LDA(3, swzk1);
    if (t < 15) SAI0(t + 1, q);
    PH_TAIL;
    MMROW(0, a0); MMROW(1, a1); MMROW(2, a2); MMROW(3, a3);
    PH_END;
    // ph4
    a0 = LDA(4, swzk1); a1 = LDA(5, swzk1); a2 = LDA(6, swzk1); a3 = LDA(7, swzk1);
    if (t < 15) {
      SAI1(t + 1, q);
      asm volatile("s_waitcnt vmcnt(2)" ::: "memory");
    }
    PH_TAIL;
    MMROW(4, a0); MMROW(5, a1); MMROW(6, a2); MMROW(7, a3);
    PH_END;
  }

  const int rsub = (l >> 4) * 4;
  if (MODE == 0) {
#pragma unroll
    for (int mf = 0; mf < 8; mf++)
#pragma unroll
      for (int j = 0; j < 4; j++) {
        const int row = m0 + mh * 128 + mf * 16 + rsub + j;
        short* Up = U + (size_t)row * HS + bx * 128 + wn4 * 32 + lr;
#pragma unroll
        for (int nfp = 0; nfp < 2; nfp++) {
          const float a = acc[mf][nfp][j];
          const float b = acc[mf][nfp + 2][j];
          Up[nfp * 16] = f2b(a / (1.f + expf(-a)) * b);
        }
      }
  } else if (MODE == 1) {
#pragma unroll
    for (int mf = 0; mf < 8; mf++)
#pragma unroll
      for (int j = 0; j < 4; j++) {
        const int gi = rbeg + m0 + mh * 128 + mf * 16 + rsub + j;
        if (gi < rend) {
          short* Cp = U + (size_t)gi * HE + bx * 256 + wn4 * 64 + lr;
#pragma unroll
          for (int nf = 0; nf < 4; nf++) {
            const float v = acc[mf][nf][j];
            Cp[nf * 16] = f2b(0.5f * v * (1.0f + erff(v * 0.70710678118654752f)));
          }
        }
      }
  } else {
#pragma unroll
    for (int mf = 0; mf < 8; mf++)
#pragma unroll
      for (int j = 0; j < 4; j++) {
        const int gi = rbeg + m0 + mh * 128 + mf * 16 + rsub + j;
        if (gi < rend) {
          const int slot = perm[gi];
          const float g = gates[slot];
          short* Cp = U + (size_t)slot * D_MODEL + bx * 256 + wn4 * 64 + lr;
#pragma unroll
          for (int nf = 0; nf < 4; nf++) Cp[nf * 16] = f2b(g * acc[mf][nf][j]);
        }
      }
  }
#undef SB0
#undef SB1
#undef SAI0
#undef SAI1
#undef LDA
#undef LDB
#undef MMROW
#undef PH_TAIL
#undef PH_END
}

// ---------------- G2: shared = u @ w2, fused final combine (2-phase 128²) ----
__global__ __launch_bounds__(256, 2) void gemm_g2(
    const short* __restrict__ A, const short* __restrict__ B,
    const short* __restrict__ yb, float* __restrict__ out) {
  __shared__ __align__(16) short As[4096];
  __shared__ __align__(16) short Bs[4096];
  const int t = threadIdx.x;
  const int tile_n = blockIdx.x * 128;  // over D_MODEL
  const int m0 = blockIdx.y * 128;
  const int r = t >> 2;
  const int c8 = (t & 3) * 8;
  const short* Ap0 = A + (size_t)(m0 + r) * HS + c8;
  const short* Ap1 = A + (size_t)(m0 + 64 + r) * HS + c8;
  const short* Bp0 = B + (size_t)(tile_n + r) * HS + c8;
  const short* Bp1 = B + (size_t)(tile_n + 64 + r) * HS + c8;

  const int lane = t & 63, wv = t >> 6;
  const int wm = (wv >> 1) * 64, wn = (wv & 1) * 64;
  const int lr = lane & 15, lk = (lane >> 4) * 8;

  f32x4 acc[4][4] = {};
  for (int k0 = 0; k0 < HS; k0 += 32) {
    gl_lds16(Ap0 + k0, &As[t * 8]);
    gl_lds16(Ap1 + k0, &As[2048 + t * 8]);
    gl_lds16(Bp0 + k0, &Bs[t * 8]);
    gl_lds16(Bp1 + k0, &Bs[2048 + t * 8]);
    __syncthreads();
    bf16x8 af[4], bfr[4];
#pragma unroll
    for (int m = 0; m < 4; m++) af[m] = *(const bf16x8*)&As[(wm + m * 16 + lr) * 32 + lk];
#pragma unroll
    for (int n = 0; n < 4; n++) bfr[n] = *(const bf16x8*)&Bs[(wn + n * 16 + lr) * 32 + lk];
#pragma unroll
    for (int m = 0; m < 4; m++)
#pragma unroll
      for (int n = 0; n < 4; n++)
        acc[m][n] = __builtin_amdgcn_mfma_f32_16x16x32_bf16(af[m], bfr[n], acc[m][n], 0, 0, 0);
    __syncthreads();
  }

  const int rq = (lane >> 4) * 4;
  const float inv3 = 1.0f / 3.0f;
#pragma unroll
  for (int m = 0; m < 4; m++) {
#pragma unroll
    for (int j = 0; j < 4; j++) {
      const int tok = m0 + wm + m * 16 + rq + j;
      const int colb = tile_n + wn + lr;
      const short* y0p = yb + (size_t)(tok * 2) * D_MODEL + colb;
      const short* y1p = yb + (size_t)(tok * 2 + 1) * D_MODEL + colb;
      float* Op = out + (size_t)tok * D_MODEL + colb;
#pragma unroll
      for (int n = 0; n < 4; n++) {
        Op[n * 16] = (acc[m][n][j] + b2f(y0p[n * 16]) + b2f(y1p[n * 16])) * inv3;
      }
    }
  }
}

// ---------------- launch ----------------
extern "C" void kernel_launch(void* const* d_in, const int* in_sizes, int n_in,
                              void* d_out, int out_size, void* d_ws, size_t ws_size,
                              hipStream_t stream) {
  const float* x = (const float*)d_in[0];
  const float* temb = (const float*)d_in[1];
  const float* rw = (const float*)d_in[2];
  const float* rbias = (const float*)d_in[3];
  const float* w1 = (const float*)d_in[4];
  const float* w3 = (const float*)d_in[5];
  const float* w2 = (const float*)d_in[6];
  const float* W1e = (const float*)d_in[7];
  const float* W2e = (const float*)d_in[8];
  float* out = (float*)d_out;

  const size_t MB = 1ull << 20;
  char* w = (char*)d_ws;
  short* xb    = (short*)(w + 0 * MB);    // 8 MB  [4096][1024]
  short* w13I  = (short*)(w + 8 * MB);    // 8 MB  [4096][1024] interleaved w1/w3
  short* w2T   = (short*)(w + 16 * MB);   // 4 MB  [1024][2048]
  short* W1eT  = (short*)(w + 20 * MB);   // 16 MB [8][1024][1024]
  short* W2eT  = (short*)(w + 36 * MB);   // 16 MB [8][1024][1024]
  short* ubuf  = (short*)(w + 52 * MB);   // 16 MB [4096][2048]
  short* hexpb = (short*)(w + 68 * MB);   // 16 MB [8192][1024]
  short* yb    = (short*)(w + 84 * MB);   // 16 MB [8192][1024] gated bf16
  float* gates = (float*)(w + 100 * MB);  // 32 KB
  int* topk    = (int*)(w + 100 * MB + 32 * 1024);
  int* perm    = (int*)(w + 100 * MB + 64 * 1024);
  int* offs    = (int*)(w + 100 * MB + 96 * 1024);

  hipFuncSetAttribute((const void*)&moe_gemm_8ph<0>,
                      hipFuncAttributeMaxDynamicSharedMemorySize, 131072);
  hipFuncSetAttribute((const void*)&moe_gemm_8ph<1>,
                      hipFuncAttributeMaxDynamicSharedMemorySize, 131072);
  hipFuncSetAttribute((const void*)&moe_gemm_8ph<2>,
                      hipFuncAttributeMaxDynamicSharedMemorySize, 131072);

  // one fused prep launch: cvt_x + all transposes + router
  prep_kernel<<<8704, 256, 0, stream>>>(x, temb, rw, rbias, w1, w3, w2, W1e, W2e,
                                        xb, w13I, w2T, W1eT, W2eT, topk, gates);
  group_kernel<<<1, 1024, 0, stream>>>(topk, perm, offs);

  // G1: u = silu(x@w1)*(x@w3)
  moe_gemm_8ph<0><<<dim3(HS / 128, NTOK / 256, 1), 512, 131072, stream>>>(
      xb, w13I, ubuf, nullptr, nullptr, nullptr);

  // routed experts
  moe_gemm_8ph<1><<<dim3(HE / 256, 32, NEXP), 512, 131072, stream>>>(
      xb, W1eT, hexpb, perm, offs, gates);
  moe_gemm_8ph<2><<<dim3(D_MODEL / 256, 32, NEXP), 512, 131072, stream>>>(
      hexpb, W2eT, yb, perm, offs, gates);

  // shared down-proj + final combine
  gemm_g2<<<dim3(D_MODEL / 128, NTOK / 128, 1), 256, 0, stream>>>(ubuf, w2T, yb, out);
}

// Round 7
// 253.728 us; speedup vs baseline: 1.2004x; 1.2004x over previous
//
#include <hip/hip_runtime.h>
#include <hip/hip_bf16.h>
#include <math.h>

#define D_MODEL 1024
#define HS 2048
#define HE 1024
#define NEXP 8
#define NTOK 4096
#define NSLOT 8192

typedef __attribute__((ext_vector_type(4))) float f32x4;
typedef __attribute__((ext_vector_type(8))) short bf16x8;

__device__ __forceinline__ short f2b(float f) {
  __hip_bfloat16 h = __float2bfloat16(f);
  return *reinterpret_cast<short*>(&h);
}
__device__ __forceinline__ float b2f(short s) {
  return __bfloat162float(*reinterpret_cast<__hip_bfloat16*>(&s));
}

__device__ __forceinline__ void gl_lds16(const short* g, short* l) {
  __builtin_amdgcn_global_load_lds(
      (const __attribute__((address_space(1))) void*)g,
      (__attribute__((address_space(3))) void*)l, 16, 0, 0);
}

// ---------------- converts (separate launches: R5-proven; fused prep regressed R6) ----
__global__ __launch_bounds__(256) void cvt_x_kernel(const float* __restrict__ in,
                                                    short* __restrict__ out) {
  int i = blockIdx.x * 256 + threadIdx.x;  // over NTOK*D/4
  const float4 v = ((const float4*)in)[i];
  short4 o;
  o.x = f2b(v.x); o.y = f2b(v.y); o.z = f2b(v.z); o.w = f2b(v.w);
  ((short4*)out)[i] = o;
}

// in [R][C] f32 -> out bf16 transposed. RMAP: 0 plain [C][R]; 1/2: w13I
// interleaved row remap: out_row = (c>>5)*64 + (RMAP==2?32:0) + (c&31).
template <int RMAP>
__global__ __launch_bounds__(256) void transpose_cvt(const float* __restrict__ in,
                                                     short* __restrict__ out,
                                                     int R, int C) {
  __shared__ float tile[64][69];  // tile[col][row]
  const int t = threadIdx.x;
  const int c0 = blockIdx.x * 64;
  const int r0 = blockIdx.y * 64;
  const size_t bo = (size_t)blockIdx.z * R * C;
  const int lr = t >> 4;          // 0..15
  const int lc4 = (t & 15) * 4;   // 0..60
#pragma unroll
  for (int i = 0; i < 4; i++) {
    const float4 v = *(const float4*)&in[bo + (size_t)(r0 + lr + i * 16) * C + c0 + lc4];
    tile[lc4 + 0][lr + i * 16] = v.x;
    tile[lc4 + 1][lr + i * 16] = v.y;
    tile[lc4 + 2][lr + i * 16] = v.z;
    tile[lc4 + 3][lr + i * 16] = v.w;
  }
  __syncthreads();
#pragma unroll
  for (int i = 0; i < 4; i++) {
    const int oc = (t >> 4) + i * 16;  // local out row (= in col)
    const int or4 = (t & 15) * 4;      // local out col (= in row)
    short4 o;
    o.x = f2b(tile[oc][or4 + 0]);
    o.y = f2b(tile[oc][or4 + 1]);
    o.z = f2b(tile[oc][or4 + 2]);
    o.w = f2b(tile[oc][or4 + 3]);
    const int c = c0 + oc;
    size_t orow;
    if (RMAP == 0) orow = bo + (size_t)c * R;
    else orow = (size_t)((c >> 5) * 64 + (RMAP == 2 ? 32 : 0) + (c & 31)) * R;
    *(short4*)&out[orow + r0 + or4] = o;
  }
}

// ---------------- router (wave per token, float4) ----------------
__global__ __launch_bounds__(256) void router_kernel(
    const float* __restrict__ x, const float* __restrict__ temb,
    const float* __restrict__ rw, const float* __restrict__ rbias,
    int* __restrict__ topk, float* __restrict__ gates) {
  const int t = (blockIdx.x * 256 + threadIdx.x) >> 6;
  const int lane = threadIdx.x & 63;
  const float* xr = x + (size_t)t * D_MODEL;
  const float* tr = temb + (size_t)(t >> 10) * D_MODEL;  // T=1024
  float acc[NEXP] = {};
#pragma unroll
  for (int i = 0; i < 4; i++) {
    const int j = i * 256 + lane * 4;
    const float4 xv = *(const float4*)&xr[j];
    const float4 tv = *(const float4*)&tr[j];
    const float* wx = rw + (size_t)j * NEXP;
    const float* wt = rw + (size_t)(D_MODEL + j) * NEXP;
    const float xa[4] = {xv.x, xv.y, xv.z, xv.w};
    const float ta[4] = {tv.x, tv.y, tv.z, tv.w};
#pragma unroll
    for (int u = 0; u < 4; u++)
#pragma unroll
      for (int e = 0; e < NEXP; e++)
        acc[e] += xa[u] * wx[u * NEXP + e] + ta[u] * wt[u * NEXP + e];
  }
#pragma unroll
  for (int off = 32; off; off >>= 1)
#pragma unroll
    for (int e = 0; e < NEXP; e++) acc[e] += __shfl_xor(acc[e], off);
  if (lane == 0) {
    float s[NEXP], sel[NEXP];
#pragma unroll
    for (int e = 0; e < NEXP; e++) {
      s[e] = 1.f / (1.f + expf(-acc[e]));
      sel[e] = s[e] + rbias[e];
    }
    int i0 = 0;
#pragma unroll
    for (int e = 1; e < NEXP; e++) if (sel[e] > sel[i0]) i0 = e;
    int i1 = (i0 == 0) ? 1 : 0;
#pragma unroll
    for (int e = 0; e < NEXP; e++) if (e != i0 && sel[e] > sel[i1]) i1 = e;
    float s0 = s[i0], s1 = s[i1], den = s0 + s1;
    float g0, g1;
    if (den > 1e-9f) { g0 = s0 / (den + 1e-9f); g1 = s1 / (den + 1e-9f); }
    else { g0 = 0.5f; g1 = 0.5f; }
    topk[t * 2] = i0; topk[t * 2 + 1] = i1;
    gates[t * 2] = g0; gates[t * 2 + 1] = g1;
  }
}

// ---------------- grouping: hist + scan + fill in one block ----------------
__global__ __launch_bounds__(1024) void group_kernel(const int* __restrict__ topk,
                                                     int* __restrict__ perm,
                                                     int* __restrict__ offs) {
  __shared__ int cnt[NEXP], cur[NEXP];
  const int t = threadIdx.x;
  if (t < NEXP) cnt[t] = 0;
  __syncthreads();
  int mye[8];
#pragma unroll
  for (int i = 0; i < 8; i++) {
    mye[i] = topk[i * 1024 + t];
    atomicAdd(&cnt[mye[i]], 1);
  }
  __syncthreads();
  if (t == 0) {
    int a = 0;
    for (int e = 0; e < NEXP; e++) { offs[e] = a; cur[e] = a; a += cnt[e]; }
    offs[NEXP] = a;
  }
  __syncthreads();
#pragma unroll
  for (int i = 0; i < 8; i++) {
    int pos = atomicAdd(&cur[mye[i]], 1);
    perm[pos] = i * 1024 + t;
  }
}

// ========== G1: 256x256 BK=64 per-phase-barrier 8-wave (R5-proven) ==========
__global__ __launch_bounds__(512, 1) void gemm_g1_8ph(
    const short* __restrict__ A, const short* __restrict__ B, short* __restrict__ U) {
  extern __shared__ short lds[];
  const int td = threadIdx.x;
  const int bx = blockIdx.x;
  const int m0 = blockIdx.y * 256;
  const short* Bbase = B + (size_t)bx * 256 * 1024;

  const int srow = td >> 3;
  const int colsw8 = ((td & 7) ^ (srow & 7)) * 8;
  const short* ap[2][2];
  const short* bp[2][2];
#pragma unroll
  for (int h = 0; h < 2; h++)
#pragma unroll
    for (int i = 0; i < 2; i++) {
      const int trow = h * 128 + i * 64 + srow;
      ap[h][i] = A + (size_t)(m0 + trow) * 1024 + colsw8;
      bp[h][i] = Bbase + (size_t)trow * 1024 + colsw8;
    }

#define SB0(t_, b_)                                                        \
  do {                                                                     \
    gl_lds16(bp[0][0] + (t_) * 64, lds + (b_) * 32768 + 16384 + td * 8);   \
    gl_lds16(bp[0][1] + (t_) * 64, lds + (b_) * 32768 + 16384 + 4096 + td * 8); \
  } while (0)
#define SB1(t_, b_)                                                        \
  do {                                                                     \
    gl_lds16(bp[1][0] + (t_) * 64, lds + (b_) * 32768 + 16384 + 8192 + td * 8); \
    gl_lds16(bp[1][1] + (t_) * 64, lds + (b_) * 32768 + 16384 + 8192 + 4096 + td * 8); \
  } while (0)
#define SAI0(t_, b_)                                                       \
  do {                                                                     \
    gl_lds16(ap[0][0] + (t_) * 64, lds + (b_) * 32768 + td * 8);           \
    gl_lds16(ap[1][0] + (t_) * 64, lds + (b_) * 32768 + 8192 + td * 8);    \
  } while (0)
#define SAI1(t_, b_)                                                       \
  do {                                                                     \
    gl_lds16(ap[0][1] + (t_) * 64, lds + (b_) * 32768 + 4096 + td * 8);    \
    gl_lds16(ap[1][1] + (t_) * 64, lds + (b_) * 32768 + 8192 + 4096 + td * 8); \
  } while (0)

  const int l = td & 63;
  const int wid = td >> 6;
  const int mh = wid >> 2;
  const int wn4 = wid & 3;
  const int lr = l & 15;
  const int bhsel = wn4 >> 1;
  const int bnr = (wn4 & 1) * 64;
  const int swzk0 = ((0 + (l >> 4) * 16) ^ ((l & 7) << 4)) >> 1;
  const int swzk1 = ((64 + (l >> 4) * 16) ^ ((l & 7) << 4)) >> 1;

#define LDA(mf_, swz_) (*(const bf16x8*)&Ah[(unsigned)(((mf_)*16 + lr) * 64) + (swz_)])
#define LDB(nf_, swz_) (*(const bf16x8*)&Bh[(unsigned)((bnr + (nf_)*16 + lr) * 64) + (swz_)])
#define MMROW(mf_, a_)                                                                 \
  acc[mf_][0] = __builtin_amdgcn_mfma_f32_16x16x32_bf16(a_, b0, acc[mf_][0], 0, 0, 0); \
  acc[mf_][1] = __builtin_amdgcn_mfma_f32_16x16x32_bf16(a_, b1, acc[mf_][1], 0, 0, 0); \
  acc[mf_][2] = __builtin_amdgcn_mfma_f32_16x16x32_bf16(a_, b2, acc[mf_][2], 0, 0, 0); \
  acc[mf_][3] = __builtin_amdgcn_mfma_f32_16x16x32_bf16(a_, b3, acc[mf_][3], 0, 0, 0)

#define PH_TAIL                                   \
  __builtin_amdgcn_s_barrier();                   \
  asm volatile("s_waitcnt lgkmcnt(0)" ::: "memory"); \
  __builtin_amdgcn_sched_barrier(0);              \
  __builtin_amdgcn_s_setprio(1)
#define PH_END                                    \
  __builtin_amdgcn_s_setprio(0);                  \
  __builtin_amdgcn_s_barrier();                   \
  __builtin_amdgcn_sched_barrier(0)

  f32x4 acc[8][4] = {};

  SB0(0, 0); SB1(0, 0); SAI0(0, 0); SAI1(0, 0);
  asm volatile("s_waitcnt vmcnt(2)" ::: "memory");
  __builtin_amdgcn_s_barrier();

  for (int t = 0; t < 16; ++t) {
    const int p = t & 1, q = p ^ 1;
    const short* Ah = lds + p * 32768 + mh * 8192;
    const short* Bh = lds + p * 32768 + 16384 + bhsel * 8192;
    bf16x8 b0, b1, b2, b3, a0, a1, a2, a3;
    // ph1
    b0 = LDB(0, swzk0); b1 = LDB(1, swzk0); b2 = LDB(2, swzk0); b3 = LDB(3, swzk0);
    a0 = LDA(0, swzk0); a1 = LDA(1, swzk0); a2 = LDA(2, swzk0); a3 = LDA(3, swzk0);
    if (t < 15) {
      SB0(t + 1, q);
      asm volatile("s_waitcnt vmcnt(2)" ::: "memory");
    } else {
      asm volatile("s_waitcnt vmcnt(0)" ::: "memory");
    }
    PH_TAIL;
    MMROW(0, a0); MMROW(1, a1); MMROW(2, a2); MMROW(3, a3);
    PH_END;
    // ph2
    a0 = LDA(4, swzk0); a1 = LDA(5, swzk0); a2 = LDA(6, swzk0); a3 = LDA(7, swzk0);
    if (t < 15) SB1(t + 1, q);
    PH_TAIL;
    MMROW(4, a0); MMROW(5, a1); MMROW(6, a2); MMROW(7, a3);
    PH_END;
    // ph3
    b0 = LDB(0, swzk1); b1 = LDB(1, swzk1); b2 = LDB(2, swzk1); b3 = LDB(3, swzk1);
    a0 = LDA(0, swzk1); a1 = LDA(1, swzk1); a2 = LDA(2, swzk1); a3 = LDA(3, swzk1);
    if (t < 15) SAI0(t + 1, q);
    PH_TAIL;
    MMROW(0, a0); MMROW(1, a1); MMROW(2, a2); MMROW(3, a3);
    PH_END;
    // ph4
    a0 = LDA(4, swzk1); a1 = LDA(5, swzk1); a2 = LDA(6, swzk1); a3 = LDA(7, swzk1);
    if (t < 15) {
      SAI1(t + 1, q);
      asm volatile("s_waitcnt vmcnt(2)" ::: "memory");
    }
    PH_TAIL;
    MMROW(4, a0); MMROW(5, a1); MMROW(6, a2); MMROW(7, a3);
    PH_END;
  }

  const int rsub = (l >> 4) * 4;
#pragma unroll
  for (int mf = 0; mf < 8; mf++)
#pragma unroll
    for (int j = 0; j < 4; j++) {
      const int row = m0 + mh * 128 + mf * 16 + rsub + j;
      short* Up = U + (size_t)row * HS + bx * 128 + wn4 * 32 + lr;
#pragma unroll
      for (int nfp = 0; nfp < 2; nfp++) {
        const float a = acc[mf][nfp][j];
        const float b = acc[mf][nfp + 2][j];
        Up[nfp * 16] = f2b(a / (1.f + expf(-a)) * b);
      }
    }
#undef SB0
#undef SB1
#undef SAI0
#undef SAI1
#undef LDA
#undef LDB
#undef MMROW
#undef PH_TAIL
#undef PH_END
}

// ========== grouped: 128x256 BK=64, 3-buffer deep pipeline, full fill ==========
// MODE 1: A=xb gathered perm>>1, GELU -> hexpb[gi].  grid(4, 64, 8)
// MODE 2: A=hexpb slot-dense, gate*scatter -> yb.     grid(4, 64, 8)
// 8 waves as 2M x 4N; per-wave 64x64 out (acc[4][4]). K=1024, 16 K-tiles.
// LDS 144 KiB = 3 bufs x {A[128][64] | B[256][64]} (24576 shorts each).
// Stage tile t+2 during tile t (units: ph1 B0,B1; ph2 B2,B3; ph3 A0,A1).
// One vmcnt(6) at ph4-end covers ALL of tile t+1, leaves t+2's 6 in flight.
template <int MODE>
__global__ __launch_bounds__(512, 1) void moe_grp_8ph(
    const short* __restrict__ A, const short* __restrict__ B, short* __restrict__ Cout,
    const int* __restrict__ perm, const int* __restrict__ offs,
    const float* __restrict__ gates) {
  extern __shared__ short lds[];
  const int td = threadIdx.x;
  const int bx = blockIdx.x;        // 256-col N tile
  const int m0 = blockIdx.y * 128;  // 128-row M tile
  const int e = blockIdx.z;
  const int rbeg = offs[e], rend = offs[e + 1];
  if (m0 >= rend - rbeg) return;
  const short* Bbase = B + ((size_t)e * 1024 + bx * 256) * 1024;

  const int srow = td >> 3;
  const int colsw8 = ((td & 7) ^ (srow & 7)) * 8;
  const short* apx[2];
  const short* bpx[4];
#pragma unroll
  for (int i = 0; i < 2; i++) {
    const int trow = i * 64 + srow;
    int grow;
    if (MODE == 1) grow = perm[min(rbeg + m0 + trow, rend - 1)] >> 1;
    else grow = min(rbeg + m0 + trow, rend - 1);
    apx[i] = A + (size_t)grow * 1024 + colsw8;
  }
#pragma unroll
  for (int u = 0; u < 4; u++)
    bpx[u] = Bbase + (size_t)(u * 64 + srow) * 1024 + colsw8;

#define SA(i_, t_, b_) gl_lds16(apx[i_] + (t_) * 64, lds + (b_) * 24576 + (i_) * 4096 + td * 8)
#define SB(u_, t_, b_) gl_lds16(bpx[u_] + (t_) * 64, lds + (b_) * 24576 + 8192 + (u_) * 4096 + td * 8)

  const int l = td & 63;
  const int wid = td >> 6;
  const int mh = wid >> 2;          // 0,1: 64-row half of the 128-row tile
  const int wn4 = wid & 3;          // 64-col quarter (and B unit index)
  const int lr = l & 15;
  const int swzk0 = ((0 + (l >> 4) * 16) ^ ((l & 7) << 4)) >> 1;
  const int swzk1 = ((64 + (l >> 4) * 16) ^ ((l & 7) << 4)) >> 1;

#define LDA(mf_, swz_) (*(const bf16x8*)&Ah[(unsigned)(((mf_)*16 + lr) * 64) + (swz_)])
#define LDB(nf_, swz_) (*(const bf16x8*)&Bh[(unsigned)(((nf_)*16 + lr) * 64) + (swz_)])
#define MMROW(mf_, a_)                                                                 \
  acc[mf_][0] = __builtin_amdgcn_mfma_f32_16x16x32_bf16(a_, b0, acc[mf_][0], 0, 0, 0); \
  acc[mf_][1] = __builtin_amdgcn_mfma_f32_16x16x32_bf16(a_, b1, acc[mf_][1], 0, 0, 0); \
  acc[mf_][2] = __builtin_amdgcn_mfma_f32_16x16x32_bf16(a_, b2, acc[mf_][2], 0, 0, 0); \
  acc[mf_][3] = __builtin_amdgcn_mfma_f32_16x16x32_bf16(a_, b3, acc[mf_][3], 0, 0, 0)

#define PH_TAIL                                   \
  __builtin_amdgcn_s_barrier();                   \
  asm volatile("s_waitcnt lgkmcnt(0)" ::: "memory"); \
  __builtin_amdgcn_sched_barrier(0);              \
  __builtin_amdgcn_s_setprio(1)
#define PH_END                                    \
  __builtin_amdgcn_s_setprio(0);                  \
  __builtin_amdgcn_s_barrier();                   \
  __builtin_amdgcn_sched_barrier(0)

  f32x4 acc[4][4] = {};

  // prologue: stage tiles 0 (buf0) and 1 (buf1); ensure tile 0 landed (leave 6)
  SA(0, 0, 0); SA(1, 0, 0); SB(0, 0, 0); SB(1, 0, 0); SB(2, 0, 0); SB(3, 0, 0);
  SA(0, 1, 1); SA(1, 1, 1); SB(0, 1, 1); SB(1, 1, 1); SB(2, 1, 1); SB(3, 1, 1);
  asm volatile("s_waitcnt vmcnt(6)" ::: "memory");
  __builtin_amdgcn_s_barrier();

  int pb = 0;  // buffer of tile t
  int sb = 2;  // buffer of tile t+2 (stage target)
  for (int t = 0; t < 16; ++t) {
    const short* Ah = lds + pb * 24576 + mh * 4096;
    const short* Bh = lds + pb * 24576 + 8192 + wn4 * 4096;
    bf16x8 b0, b1, b2, b3, a0, a1;
    // ph1: k0, mf0-1
    b0 = LDB(0, swzk0); b1 = LDB(1, swzk0); b2 = LDB(2, swzk0); b3 = LDB(3, swzk0);
    a0 = LDA(0, swzk0); a1 = LDA(1, swzk0);
    if (t <= 13) { SB(0, t + 2, sb); SB(1, t + 2, sb); }
    PH_TAIL;
    MMROW(0, a0); MMROW(1, a1);
    PH_END;
    // ph2: k0, mf2-3 (b regs held)
    a0 = LDA(2, swzk0); a1 = LDA(3, swzk0);
    if (t <= 13) { SB(2, t + 2, sb); SB(3, t + 2, sb); }
    PH_TAIL;
    MMROW(2, a0); MMROW(3, a1);
    PH_END;
    // ph3: k1, mf0-1
    b0 = LDB(0, swzk1); b1 = LDB(1, swzk1); b2 = LDB(2, swzk1); b3 = LDB(3, swzk1);
    a0 = LDA(0, swzk1); a1 = LDA(1, swzk1);
    if (t <= 13) { SA(0, t + 2, sb); SA(1, t + 2, sb); }
    PH_TAIL;
    MMROW(0, a0); MMROW(1, a1);
    PH_END;
    // ph4: k1, mf2-3; then the per-tile wait covering tile t+1
    a0 = LDA(2, swzk1); a1 = LDA(3, swzk1);
    PH_TAIL;
    MMROW(2, a0); MMROW(3, a1);
    __builtin_amdgcn_s_setprio(0);
    if (t < 14) {
      asm volatile("s_waitcnt vmcnt(6)" ::: "memory");  // t+1 landed; t+2 in flight
    } else {
      asm volatile("s_waitcnt vmcnt(0)" ::: "memory");  // tail drain
    }
    __builtin_amdgcn_s_barrier();
    __builtin_amdgcn_sched_barrier(0);
    pb = (pb == 2) ? 0 : pb + 1;
    sb = (sb == 2) ? 0 : sb + 1;
  }

  // ---- epilogue ----
  const int rsub = (l >> 4) * 4;
#pragma unroll
  for (int mf = 0; mf < 4; mf++)
#pragma unroll
    for (int j = 0; j < 4; j++) {
      const int gi = rbeg + m0 + mh * 64 + mf * 16 + rsub + j;
      if (gi < rend) {
        if (MODE == 1) {
          short* Cp = Cout + (size_t)gi * HE + bx * 256 + wn4 * 64 + lr;
#pragma unroll
          for (int nf = 0; nf < 4; nf++) {
            const float v = acc[mf][nf][j];
            Cp[nf * 16] = f2b(0.5f * v * (1.0f + erff(v * 0.70710678118654752f)));
          }
        } else {
          const int slot = perm[gi];
          const float g = gates[slot];
          short* Cp = Cout + (size_t)slot * D_MODEL + bx * 256 + wn4 * 64 + lr;
#pragma unroll
          for (int nf = 0; nf < 4; nf++) Cp[nf * 16] = f2b(g * acc[mf][nf][j]);
        }
      }
    }
#undef SA
#undef SB
#undef LDA
#undef LDB
#undef MMROW
#undef PH_TAIL
#undef PH_END
}

// ---------------- G2: shared = u @ w2, fused final combine (2-phase 128²) ----
__global__ __launch_bounds__(256, 2) void gemm_g2(
    const short* __restrict__ A, const short* __restrict__ B,
    const short* __restrict__ yb, float* __restrict__ out) {
  __shared__ __align__(16) short As[4096];
  __shared__ __align__(16) short Bs[4096];
  const int t = threadIdx.x;
  const int tile_n = blockIdx.x * 128;  // over D_MODEL
  const int m0 = blockIdx.y * 128;
  const int r = t >> 2;
  const int c8 = (t & 3) * 8;
  const short* Ap0 = A + (size_t)(m0 + r) * HS + c8;
  const short* Ap1 = A + (size_t)(m0 + 64 + r) * HS + c8;
  const short* Bp0 = B + (size_t)(tile_n + r) * HS + c8;
  const short* Bp1 = B + (size_t)(tile_n + 64 + r) * HS + c8;

  const int lane = t & 63, wv = t >> 6;
  const int wm = (wv >> 1) * 64, wn = (wv & 1) * 64;
  const int lr = lane & 15, lk = (lane >> 4) * 8;

  f32x4 acc[4][4] = {};
  for (int k0 = 0; k0 < HS; k0 += 32) {
    gl_lds16(Ap0 + k0, &As[t * 8]);
    gl_lds16(Ap1 + k0, &As[2048 + t * 8]);
    gl_lds16(Bp0 + k0, &Bs[t * 8]);
    gl_lds16(Bp1 + k0, &Bs[2048 + t * 8]);
    __syncthreads();
    bf16x8 af[4], bfr[4];
#pragma unroll
    for (int m = 0; m < 4; m++) af[m] = *(const bf16x8*)&As[(wm + m * 16 + lr) * 32 + lk];
#pragma unroll
    for (int n = 0; n < 4; n++) bfr[n] = *(const bf16x8*)&Bs[(wn + n * 16 + lr) * 32 + lk];
#pragma unroll
    for (int m = 0; m < 4; m++)
#pragma unroll
      for (int n = 0; n < 4; n++)
        acc[m][n] = __builtin_amdgcn_mfma_f32_16x16x32_bf16(af[m], bfr[n], acc[m][n], 0, 0, 0);
    __syncthreads();
  }

  const int rq = (lane >> 4) * 4;
  const float inv3 = 1.0f / 3.0f;
#pragma unroll
  for (int m = 0; m < 4; m++) {
#pragma unroll
    for (int j = 0; j < 4; j++) {
      const int tok = m0 + wm + m * 16 + rq + j;
      const int colb = tile_n + wn + lr;
      const short* y0p = yb + (size_t)(tok * 2) * D_MODEL + colb;
      const short* y1p = yb + (size_t)(tok * 2 + 1) * D_MODEL + colb;
      float* Op = out + (size_t)tok * D_MODEL + colb;
#pragma unroll
      for (int n = 0; n < 4; n++) {
        Op[n * 16] = (acc[m][n][j] + b2f(y0p[n * 16]) + b2f(y1p[n * 16])) * inv3;
      }
    }
  }
}

// ---------------- launch ----------------
extern "C" void kernel_launch(void* const* d_in, const int* in_sizes, int n_in,
                              void* d_out, int out_size, void* d_ws, size_t ws_size,
                              hipStream_t stream) {
  const float* x = (const float*)d_in[0];
  const float* temb = (const float*)d_in[1];
  const float* rw = (const float*)d_in[2];
  const float* rbias = (const float*)d_in[3];
  const float* w1 = (const float*)d_in[4];
  const float* w3 = (const float*)d_in[5];
  const float* w2 = (const float*)d_in[6];
  const float* W1e = (const float*)d_in[7];
  const float* W2e = (const float*)d_in[8];
  float* out = (float*)d_out;

  const size_t MB = 1ull << 20;
  char* w = (char*)d_ws;
  short* xb    = (short*)(w + 0 * MB);    // 8 MB  [4096][1024]
  short* w13I  = (short*)(w + 8 * MB);    // 8 MB  [4096][1024] interleaved w1/w3
  short* w2T   = (short*)(w + 16 * MB);   // 4 MB  [1024][2048]
  short* W1eT  = (short*)(w + 20 * MB);   // 16 MB [8][1024][1024]
  short* W2eT  = (short*)(w + 36 * MB);   // 16 MB [8][1024][1024]
  short* ubuf  = (short*)(w + 52 * MB);   // 16 MB [4096][2048]
  short* hexpb = (short*)(w + 68 * MB);   // 16 MB [8192][1024]
  short* yb    = (short*)(w + 84 * MB);   // 16 MB [8192][1024] gated bf16
  float* gates = (float*)(w + 100 * MB);  // 32 KB
  int* topk    = (int*)(w + 100 * MB + 32 * 1024);
  int* perm    = (int*)(w + 100 * MB + 64 * 1024);
  int* offs    = (int*)(w + 100 * MB + 96 * 1024);

  hipFuncSetAttribute((const void*)&gemm_g1_8ph,
                      hipFuncAttributeMaxDynamicSharedMemorySize, 131072);
  hipFuncSetAttribute((const void*)&moe_grp_8ph<1>,
                      hipFuncAttributeMaxDynamicSharedMemorySize, 147456);
  hipFuncSetAttribute((const void*)&moe_grp_8ph<2>,
                      hipFuncAttributeMaxDynamicSharedMemorySize, 147456);

  // prep (separate launches — R5-proven; fused mega-kernel regressed in R6)
  cvt_x_kernel<<<NTOK * D_MODEL / 4 / 256, 256, 0, stream>>>(x, xb);
  transpose_cvt<1><<<dim3(HS / 64, D_MODEL / 64, 1), 256, 0, stream>>>(w1, w13I, D_MODEL, HS);
  transpose_cvt<2><<<dim3(HS / 64, D_MODEL / 64, 1), 256, 0, stream>>>(w3, w13I, D_MODEL, HS);
  transpose_cvt<0><<<dim3(D_MODEL / 64, HS / 64, 1), 256, 0, stream>>>(w2, w2T, HS, D_MODEL);
  transpose_cvt<0><<<dim3(HE / 64, D_MODEL / 64, NEXP), 256, 0, stream>>>(W1e, W1eT, D_MODEL, HE);
  transpose_cvt<0><<<dim3(D_MODEL / 64, HE / 64, NEXP), 256, 0, stream>>>(W2e, W2eT, HE, D_MODEL);
  router_kernel<<<NTOK / 4, 256, 0, stream>>>(x, temb, rw, rbias, topk, gates);
  group_kernel<<<1, 1024, 0, stream>>>(topk, perm, offs);

  // G1: u = silu(x@w1)*(x@w3)
  gemm_g1_8ph<<<dim3(HS / 128, NTOK / 256, 1), 512, 131072, stream>>>(xb, w13I, ubuf);

  // routed experts: full-fill 128x256 tiles, 3-buffer pipeline
  moe_grp_8ph<1><<<dim3(HE / 256, NSLOT / 128, NEXP), 512, 147456, stream>>>(
      xb, W1eT, hexpb, perm, offs, gates);
  moe_grp_8ph<2><<<dim3(D_MODEL / 256, NSLOT / 128, NEXP), 512, 147456, stream>>>(
      hexpb, W2eT, yb, perm, offs, gates);

  // shared down-proj + final combine
  gemm_g2<<<dim3(D_MODEL / 128, NTOK / 128, 1), 256, 0, stream>>>(ubuf, w2T, yb, out);
}